// Round 8
// baseline (37.375 us; speedup 1.0000x reference)
//
#include <hip/hip_runtime.h>

// Scatter-add inverted to gather — SINGLE plain dispatch, block-local buckets:
//   Each block owns RPB=256 consecutive output rows. It scans the whole idx
//   array (128 KB, L2-resident — all blocks read it in near-lockstep),
//   buckets matching sources into LDS via LDS atomics, then gathers its rows
//   (each output row written exactly once, no fp atomics, no global
//   metadata, no workspace, no memset, no grid sync).
// MAXD=12 padded LDS slots per row. Poisson(0.5) per row: P(cnt>12) ~ 1e-7;
// overflow is still CORRECT via a rescan-of-idx fallback per overflowing row.
//
// Revision history:
//  - r0 (40.8 us): 3 dispatches (memset, fill, gather).
//  - r1 (51.1 us): nontemporal hints — defeat L2 write-combining. Reverted.
//  - r2 (41.3 us): contiguous lane layout; gather is stream-BW-bound.
//  - r3 (331.7 us): cg grid.sync fusion — ~150 us/barrier.
//  - r4 (329.8 us): custom 2-level barrier — identical cost. Software grid
//    sync on 8-XCD gfx950 is structurally ~150 us; kernel boundary is the
//    only cheap grid barrier.
//  - r5 (41.2 us): best 3-dispatch: gather ~33 us + ~8 us fill pipeline.
//  - r6 (44.6 us): sync-free fused, RPB=32/grid=2048: scan prologue ~11 us
//    (redundant idx reads + VALU), serial before HBM phase.
//  - r7 (36.1 us): RPB=128/BLK=1024/grid=512: scan 11.2 -> 2.8 us (4x
//    redundancy cut, confirmed linear). Gather core constant ~33.3 us.
//  - r8 (this): RPB=256/BLK=1024/grid=256 (1 block/CU): last redundancy
//    doubling, scan -> ~1.4 us. Gather margin at 16 waves/CU is ~11x above
//    the per-CU BW requirement, so saturation should hold.

#define MAXD 12
#define RPB  256   // rows per block; grid = R/RPB = 256 = 1 block/CU
#define BLK  1024  // threads per block (16 waves)

typedef float f32x4 __attribute__((ext_vector_type(4)));
typedef int   i32x4 __attribute__((ext_vector_type(4)));

__global__ void __launch_bounds__(BLK) fused_bucket_gather(
        const float* __restrict__ in,
        const int* __restrict__ idx,
        float* __restrict__ out,
        int C, int n_rows, int R) {
    __shared__ int s_cnt[RPB];
    __shared__ int s_ids[RPB][MAXD];

    int base = blockIdx.x * RPB;

    for (int i = threadIdx.x; i < RPB; i += BLK) s_cnt[i] = 0;
    __syncthreads();

    // ---- Phase 1: scan idx; bucket sources landing in [base, base+RPB). ----
    // int4-vectorized: 32768/4/1024 = 8 iterations per thread. All blocks
    // scan the same 128 KB in near-lockstep -> L2 hits (~32 MB total).
    int n4 = n_rows >> 2;
    const i32x4* idx4 = reinterpret_cast<const i32x4*>(idx);
    for (int i = threadIdx.x; i < n4; i += BLK) {
        i32x4 d4 = idx4[i];
        int s0 = i << 2;
        #pragma unroll
        for (int k = 0; k < 4; ++k) {
            unsigned rel = (unsigned)(d4[k] - base);
            if (rel < (unsigned)RPB) {
                int pos = atomicAdd(&s_cnt[rel], 1);
                if (pos < MAXD) s_ids[rel][pos] = s0 + k;
            }
        }
    }
    for (int i = (n4 << 2) + threadIdx.x; i < n_rows; i += BLK) {  // tail
        unsigned rel = (unsigned)(idx[i] - base);
        if (rel < (unsigned)RPB) {
            int pos = atomicAdd(&s_cnt[rel], 1);
            if (pos < MAXD) s_ids[rel][pos] = i;
        }
    }
    __syncthreads();

    // ---- Phase 2: gather. Wave w handles rows w, w+16, ... (16 rows). ----
    int wid  = threadIdx.x >> 6;       // 0..15
    int lane = threadIdx.x & 63;

    long col0 = (long)lane * 4;             // bytes [0,1024) of the row
    long col1 = (long)(C >> 1) + lane * 4;  // bytes [1024,2048) of the row

    for (int r = wid; r < RPB; r += BLK / 64) {
        int row = base + r;
        if (row >= R) break;                // wave-uniform

        int cnt  = s_cnt[r];
        int myid = (lane < MAXD) ? s_ids[r][lane] : -1;

        f32x4 a0 = 0.f;
        f32x4 a1 = 0.f;

        int m = (cnt < MAXD) ? cnt : MAXD;
        for (int j = 0; j < m; ++j) {
            int src = __shfl(myid, j);              // wave-uniform
            const f32x4* p0 = reinterpret_cast<const f32x4*>(in + (long)src * C + col0);
            const f32x4* p1 = reinterpret_cast<const f32x4*>(in + (long)src * C + col1);
            a0 += *p0;
            a1 += *p1;
        }

        if (cnt > MAXD) {
            // Overflow fallback (P ~ 1e-7 per row; correctness guarantee):
            // rescan idx for sources of this row not captured in LDS slots.
            for (int rr = 0; rr < n_rows; ++rr) {
                if (__builtin_expect(idx[rr] == row, 0)) {
                    bool captured = __any((lane < MAXD) && (myid == rr));
                    if (!captured) {
                        const f32x4* p0 = reinterpret_cast<const f32x4*>(in + (long)rr * C + col0);
                        const f32x4* p1 = reinterpret_cast<const f32x4*>(in + (long)rr * C + col1);
                        a0 += *p0;
                        a1 += *p1;
                    }
                }
            }
        }

        *reinterpret_cast<f32x4*>(out + (long)row * C + col0) = a0;
        *reinterpret_cast<f32x4*>(out + (long)row * C + col1) = a1;
    }
}

extern "C" void kernel_launch(void* const* d_in, const int* in_sizes, int n_in,
                              void* d_out, int out_size, void* d_ws, size_t ws_size,
                              hipStream_t stream) {
    const float* in  = (const float*)d_in[0];
    const int*   idx = (const int*)d_in[1];
    float*       out = (float*)d_out;

    int n_rows = in_sizes[1];             // 32768 sources
    int C      = in_sizes[0] / n_rows;    // 512
    int R      = out_size / C;            // 65536 output rows (B*L)

    int grid = (R + RPB - 1) / RPB;       // 256 = 1 block/CU x 256 CU
    fused_bucket_gather<<<grid, BLK, 0, stream>>>(in, idx, out, C, n_rows, R);
}

// Round 9
// 36.092 us; speedup vs baseline: 1.0356x; 1.0356x over previous
//
#include <hip/hip_runtime.h>

// Scatter-add inverted to gather — SINGLE plain dispatch, block-local buckets:
//   Each block owns RPB=128 consecutive output rows. It scans the whole idx
//   array (128 KB, L2-resident — all blocks read it in near-lockstep),
//   buckets matching sources into LDS via LDS atomics, then gathers its rows
//   (each output row written exactly once, no fp atomics, no global
//   metadata, no workspace, no memset, no grid sync).
// MAXD=12 padded LDS slots per row. Poisson(0.5) per row: P(cnt>12) ~ 1e-7;
// overflow is still CORRECT via a rescan-of-idx fallback per overflowing row.
//
// Revision history:
//  - r0 (40.8 us): 3 dispatches (memset, fill, gather).
//  - r1 (51.1 us): nontemporal hints — defeat L2 write-combining. Reverted.
//  - r2 (41.3 us): contiguous lane layout; gather is stream-BW-bound.
//  - r3 (331.7 us): cg grid.sync fusion — ~150 us/barrier.
//  - r4 (329.8 us): custom 2-level barrier — identical cost. Software grid
//    sync on 8-XCD gfx950 is structurally ~150 us; kernel boundary is the
//    only cheap grid barrier.
//  - r5 (41.2 us): best 3-dispatch: gather ~33 us + ~8 us fill pipeline.
//  - r6 (44.6 us): sync-free fused, RPB=32/grid=2048: scan prologue ~11 us.
//  - r7 (36.1 us): RPB=128/BLK=1024/grid=512: scan 11.2 -> 2.8 us (4x
//    redundancy cut, linear as modeled). Gather core ~33.3 us.
//  - r8 (37.4 us): RPB=256/grid=256 (1 block/CU): scan -1.4 us but gather
//    +2.6 us — 16 waves/CU under-covers HBM latency and 1 block/CU loses
//    load-balance averaging. Scan axis bracketed; grid=512 is the optimum.
//  - r9 (this): bit-exact revert to r7. Roofline decomposition: scan ~2.8 us
//    (L2-BW floor for 512-block redundant scan), gather ~33.3 us = 164 MB
//    HBM at 4.93 TB/s ~ 70% of the 7.0 TB/s write-only ceiling, consistent
//    with DRAM read/write turnaround for the mandatory 80/20 w/r mix.

#define MAXD 12
#define RPB  128   // rows per block; grid = R/RPB = 512 = 2 blocks/CU
#define BLK  1024  // threads per block (16 waves)

typedef float f32x4 __attribute__((ext_vector_type(4)));
typedef int   i32x4 __attribute__((ext_vector_type(4)));

__global__ void __launch_bounds__(BLK) fused_bucket_gather(
        const float* __restrict__ in,
        const int* __restrict__ idx,
        float* __restrict__ out,
        int C, int n_rows, int R) {
    __shared__ int s_cnt[RPB];
    __shared__ int s_ids[RPB][MAXD];

    int base = blockIdx.x * RPB;

    for (int i = threadIdx.x; i < RPB; i += BLK) s_cnt[i] = 0;
    __syncthreads();

    // ---- Phase 1: scan idx; bucket sources landing in [base, base+RPB). ----
    // int4-vectorized: 32768/4/1024 = 8 iterations per thread. All blocks
    // scan the same 128 KB in near-lockstep -> L2 hits (~64 MB total, ~2 us).
    int n4 = n_rows >> 2;
    const i32x4* idx4 = reinterpret_cast<const i32x4*>(idx);
    for (int i = threadIdx.x; i < n4; i += BLK) {
        i32x4 d4 = idx4[i];
        int s0 = i << 2;
        #pragma unroll
        for (int k = 0; k < 4; ++k) {
            unsigned rel = (unsigned)(d4[k] - base);
            if (rel < (unsigned)RPB) {
                int pos = atomicAdd(&s_cnt[rel], 1);
                if (pos < MAXD) s_ids[rel][pos] = s0 + k;
            }
        }
    }
    for (int i = (n4 << 2) + threadIdx.x; i < n_rows; i += BLK) {  // tail
        unsigned rel = (unsigned)(idx[i] - base);
        if (rel < (unsigned)RPB) {
            int pos = atomicAdd(&s_cnt[rel], 1);
            if (pos < MAXD) s_ids[rel][pos] = i;
        }
    }
    __syncthreads();

    // ---- Phase 2: gather. Wave w handles rows w, w+16, ... (8 rows). ----
    int wid  = threadIdx.x >> 6;       // 0..15
    int lane = threadIdx.x & 63;

    long col0 = (long)lane * 4;             // bytes [0,1024) of the row
    long col1 = (long)(C >> 1) + lane * 4;  // bytes [1024,2048) of the row

    for (int r = wid; r < RPB; r += BLK / 64) {
        int row = base + r;
        if (row >= R) break;                // wave-uniform

        int cnt  = s_cnt[r];
        int myid = (lane < MAXD) ? s_ids[r][lane] : -1;

        f32x4 a0 = 0.f;
        f32x4 a1 = 0.f;

        int m = (cnt < MAXD) ? cnt : MAXD;
        for (int j = 0; j < m; ++j) {
            int src = __shfl(myid, j);              // wave-uniform
            const f32x4* p0 = reinterpret_cast<const f32x4*>(in + (long)src * C + col0);
            const f32x4* p1 = reinterpret_cast<const f32x4*>(in + (long)src * C + col1);
            a0 += *p0;
            a1 += *p1;
        }

        if (cnt > MAXD) {
            // Overflow fallback (P ~ 1e-7 per row; correctness guarantee):
            // rescan idx for sources of this row not captured in LDS slots.
            for (int rr = 0; rr < n_rows; ++rr) {
                if (__builtin_expect(idx[rr] == row, 0)) {
                    bool captured = __any((lane < MAXD) && (myid == rr));
                    if (!captured) {
                        const f32x4* p0 = reinterpret_cast<const f32x4*>(in + (long)rr * C + col0);
                        const f32x4* p1 = reinterpret_cast<const f32x4*>(in + (long)rr * C + col1);
                        a0 += *p0;
                        a1 += *p1;
                    }
                }
            }
        }

        *reinterpret_cast<f32x4*>(out + (long)row * C + col0) = a0;
        *reinterpret_cast<f32x4*>(out + (long)row * C + col1) = a1;
    }
}

extern "C" void kernel_launch(void* const* d_in, const int* in_sizes, int n_in,
                              void* d_out, int out_size, void* d_ws, size_t ws_size,
                              hipStream_t stream) {
    const float* in  = (const float*)d_in[0];
    const int*   idx = (const int*)d_in[1];
    float*       out = (float*)d_out;

    int n_rows = in_sizes[1];             // 32768 sources
    int C      = in_sizes[0] / n_rows;    // 512
    int R      = out_size / C;            // 65536 output rows (B*L)

    int grid = (R + RPB - 1) / RPB;       // 512 = 2 blocks/CU x 256 CU
    fused_bucket_gather<<<grid, BLK, 0, stream>>>(in, idx, out, C, n_rows, R);
}